// Round 15
// baseline (132.306 us; speedup 1.0000x reference)
//
#include <hip/hip_runtime.h>

#define K_CLASSES 32
#define D 128
#define EPSv 0.5f
#define ZPAD 42   // shorts per row: 21 dwords, coprime with 32 banks
#define WIN 4096  // window rows per list build (list LDS capacity)

typedef __attribute__((ext_vector_type(8))) short short8;
typedef __attribute__((ext_vector_type(4))) float f32x4;

// fp32 -> bf16 round-to-nearest-even
static __device__ inline unsigned short f2bf(float f) {
  union { float f; unsigned u; } x; x.f = f;
  unsigned r = x.u + 0x7FFFu + ((x.u >> 16) & 1u);
  return (unsigned short)(r >> 16);
}

// ---------------------------------------------------------------------------
// Partial per-class Gram via bf16 MFMA (unchanged since round 8).
// ---------------------------------------------------------------------------
__global__ __launch_bounds__(256) void class_gram_kernel(
    const float* __restrict__ Z, const int* __restrict__ Y,
    float* __restrict__ part, int* __restrict__ counts_part,
    float* __restrict__ percls_part, int m, int chunkRows) {
  const int k = blockIdx.y;
  const int c = blockIdx.x;
  const int tid = threadIdx.x;
  const int lane = tid & 63;
  const int w = tid >> 6;

  const int rowStart = c * chunkRows;
  const int rowEnd = min(m, rowStart + chunkRows);

  __shared__ int list[WIN];
  __shared__ unsigned short zs[128][ZPAD];
  __shared__ int wsum[4];

  const int p = tid >> 4;
  const int part16 = tid & 15;
  const int l15 = lane & 15;
  const int kb = (lane >> 4) * 8;
  const int rb0 = w * 2, rb1 = w * 2 + 1;

  f32x4 acc0[8], acc1[8];
#pragma unroll
  for (int cb = 0; cb < 8; ++cb) { acc0[cb] = (f32x4)(0.f); acc1[cb] = (f32x4)(0.f); }
  float colacc[8];
#pragma unroll
  for (int j = 0; j < 8; ++j) colacc[j] = 0.f;

  int matched = 0;

#define LOAD_STAGE(d0, d1, stidx)                                   \
  {                                                                 \
    _Pragma("unroll") for (int j = 0; j < 8; ++j) { d0[j] = 0.f; d1[j] = 0.f; } \
    if ((stidx) < nst) {                                            \
      const int i0 = ((stidx) << 5) + p * 2;                        \
      const int r0 = list[i0];                                      \
      const int r1 = list[i0 + 1];                                  \
      if (r0 >= 0) {                                                \
        const float* zp = Z + (size_t)r0 * D + part16 * 8;          \
        *(float4*)&d0[0] = *(const float4*)zp;                      \
        *(float4*)&d0[4] = *(const float4*)(zp + 4);                \
      }                                                             \
      if (r1 >= 0) {                                                \
        const float* zp = Z + (size_t)r1 * D + part16 * 8;          \
        *(float4*)&d1[0] = *(const float4*)zp;                      \
        *(float4*)&d1[4] = *(const float4*)(zp + 4);                \
      }                                                             \
    }                                                               \
  }

#define STAGE_BODY(s0, s1)                                          \
  {                                                                 \
    _Pragma("unroll") for (int j = 0; j < 8; ++j) colacc[j] += s0[j] + s1[j]; \
    __syncthreads();                                                \
    _Pragma("unroll") for (int j = 0; j < 8; ++j) {                 \
      const unsigned pk = (unsigned)f2bf(s0[j]) | ((unsigned)f2bf(s1[j]) << 16); \
      *(unsigned*)&zs[part16 * 8 + j][2 * p] = pk;                  \
    }                                                               \
    __syncthreads();                                                \
  }

#define MFMA_BODY()                                                 \
  {                                                                 \
    short8 fragC[8];                                                \
    _Pragma("unroll") for (int fb = 0; fb < 8; ++fb)                \
      fragC[fb] = *(const short8*)&zs[fb * 16 + l15][kb];           \
    const short8 fragR0 = *(const short8*)&zs[rb0 * 16 + l15][kb];  \
    const short8 fragR1 = *(const short8*)&zs[rb1 * 16 + l15][kb];  \
    _Pragma("unroll") for (int cb = 0; cb < 8; ++cb) {              \
      acc0[cb] = __builtin_amdgcn_mfma_f32_16x16x32_bf16(fragR0, fragC[cb], acc0[cb], 0, 0, 0); \
      acc1[cb] = __builtin_amdgcn_mfma_f32_16x16x32_bf16(fragR1, fragC[cb], acc1[cb], 0, 0, 0); \
    }                                                               \
  }

  for (int w0 = rowStart; w0 < rowEnd; w0 += WIN) {
    const int wend = min(w0 + WIN, rowEnd);
    __syncthreads();

    int run = 0;
    for (int base = w0; base < wend; base += 2048) {
      const int start = base + tid * 8;
      int yv[8];
      if (((start & 3) == 0) && start + 8 <= wend) {
        const int4 ya = *(const int4*)(Y + start);
        const int4 yb = *(const int4*)(Y + start + 4);
        yv[0] = ya.x; yv[1] = ya.y; yv[2] = ya.z; yv[3] = ya.w;
        yv[4] = yb.x; yv[5] = yb.y; yv[6] = yb.z; yv[7] = yb.w;
      } else {
#pragma unroll
        for (int e = 0; e < 8; ++e) {
          const int r = start + e;
          yv[e] = (r < wend) ? Y[r] : -1;
        }
      }
      int cnt = 0;
#pragma unroll
      for (int e = 0; e < 8; ++e) cnt += (yv[e] == k) ? 1 : 0;
      int cs = cnt;
#pragma unroll
      for (int off = 1; off < 64; off <<= 1) {
        const int nbr = __shfl_up(cs, off);
        if (lane >= off) cs += nbr;
      }
      if (lane == 63) wsum[w] = cs;
      const int excl = cs - cnt;
      __syncthreads();
      int woff = 0, ctot = 0;
#pragma unroll
      for (int ww = 0; ww < 4; ++ww) {
        const int v = wsum[ww];
        if (ww < w) woff += v;
        ctot += v;
      }
      __syncthreads();
      int pos = run + woff + excl;
#pragma unroll
      for (int e = 0; e < 8; ++e) {
        if (yv[e] == k) { list[pos] = start + e; ++pos; }
      }
      run += ctot;
    }
    const int total = run;
    matched += total;
    const int padded = (total + 31) & ~31;
    for (int i = total + tid; i < padded; i += 256) list[i] = -1;
    __syncthreads();

    const int nst = padded >> 5;
    float vA0[8], vA1[8], vB0[8], vB1[8];
    LOAD_STAGE(vA0, vA1, 0);
    LOAD_STAGE(vB0, vB1, 1);

    for (int st = 0; st < nst; st += 2) {
      STAGE_BODY(vA0, vA1);
      LOAD_STAGE(vA0, vA1, st + 2);
      MFMA_BODY();
      if (st + 1 < nst) {
        STAGE_BODY(vB0, vB1);
        LOAD_STAGE(vB0, vB1, st + 3);
        MFMA_BODY();
      }
    }
  }

  float* dst = part + ((size_t)c * K_CLASSES + k) * (D * D);
  const int l4 = lane >> 4;
#pragma unroll
  for (int cb = 0; cb < 8; ++cb)
#pragma unroll
    for (int q = 0; q < 4; ++q) {
      dst[(rb0 * 16 + l4 * 4 + q) * D + cb * 16 + l15] = acc0[cb][q];
      dst[(rb1 * 16 + l4 * 4 + q) * D + cb * 16 + l15] = acc1[cb][q];
    }

  __syncthreads();
  float* cred = (float*)&zs[0][0];
#pragma unroll
  for (int j = 0; j < 8; ++j) cred[p * 128 + part16 * 8 + j] = colacc[j];
  __syncthreads();
  if (tid < 128) {
    float s = 0.f;
#pragma unroll
    for (int pp = 0; pp < 16; ++pp) s += cred[pp * 128 + tid];
    percls_part[(c * K_CLASSES + k) * D + tid] = s;
  }
  if (tid == 0) counts_part[c * K_CLASSES + k] = matched;
}

// ---------------------------------------------------------------------------
// R1: ztpiz[k][e] = sum_c part[c][k][e], float4. Grid (16, K).
// ---------------------------------------------------------------------------
__global__ __launch_bounds__(256) void reduce1_kernel(
    const float4* __restrict__ part, float4* __restrict__ ztpiz, int nchunk) {
  const int k = blockIdx.y;
  const int e = blockIdx.x * 256 + threadIdx.x;
  float4 s = make_float4(0.f, 0.f, 0.f, 0.f);
  for (int c = 0; c < nchunk; ++c) {
    const float4 v = part[((size_t)c * K_CLASSES + k) * (D * D / 4) + e];
    s.x += v.x; s.y += v.y; s.z += v.z; s.w += v.w;
  }
  ztpiz[(size_t)k * (D * D / 4) + e] = s;
}

// ---------------------------------------------------------------------------
// R2: blocks 0..63: gram[e] = sum_k ztpiz[k][e] (parallel, L2-hot).
//     block 64: Z_mean -> out (8 accumulator chains), counts_total.
// ---------------------------------------------------------------------------
__global__ __launch_bounds__(256) void reduce2_kernel(
    const float* __restrict__ ztpiz, float* __restrict__ gram,
    const int* __restrict__ counts_part, int* __restrict__ counts_total,
    const float* __restrict__ percls_part, float* __restrict__ zmean_out,
    int nchunk, int m) {
  if (blockIdx.x < 64) {
    const int e = blockIdx.x * 256 + threadIdx.x;
    float g = 0.f;
#pragma unroll
    for (int k = 0; k < K_CLASSES; ++k) g += ztpiz[(size_t)k * D * D + e];
    gram[e] = g;
  } else {
    __shared__ float buf[256];
    const int col = threadIdx.x & 127;
    const int half = threadIdx.x >> 7;
    const int np = nchunk * K_CLASSES;
    float s0 = 0.f, s1 = 0.f, s2 = 0.f, s3 = 0.f;
    float s4 = 0.f, s5 = 0.f, s6 = 0.f, s7 = 0.f;
    int i = half;
    for (; i + 14 < np; i += 16) {
      s0 += percls_part[(i)*D + col];
      s1 += percls_part[(i + 2) * D + col];
      s2 += percls_part[(i + 4) * D + col];
      s3 += percls_part[(i + 6) * D + col];
      s4 += percls_part[(i + 8) * D + col];
      s5 += percls_part[(i + 10) * D + col];
      s6 += percls_part[(i + 12) * D + col];
      s7 += percls_part[(i + 14) * D + col];
    }
    for (; i < np; i += 2) s0 += percls_part[i * D + col];
    buf[threadIdx.x] = ((s0 + s1) + (s2 + s3)) + ((s4 + s5) + (s6 + s7));
    __syncthreads();
    if (threadIdx.x < 128)
      zmean_out[threadIdx.x] = (buf[threadIdx.x] + buf[threadIdx.x + 128]) / (float)m;
    if (threadIdx.x < K_CLASSES) {
      int t = 0;
      for (int c = 0; c < nchunk; ++c) t += counts_part[c * K_CLASSES + threadIdx.x];
      counts_total[threadIdx.x] = t;
    }
  }
}

// ---------------------------------------------------------------------------
// Blocked Cholesky of I + s*G: rank-8 right-looking, 512 threads, 2 barriers
// per step (r13 was 3). The next step's 8x8 diag block is factored IN
// REGISTERS by its 2 owner threads (adjacent tids, same wave -- verified for
// all 15 pairs) via 2-lane shuffles at the END of the trailing phase, hidden
// under the other ~270 threads' 256-FMA trailing work. Phase 1 and the diag
// LDS staging of r13 are gone. Steps: 15 (step 15 is provably empty).
// Barriers: 1 prologue + 30 loop (r13: 48).
// ---------------------------------------------------------------------------
__global__ __launch_bounds__(512) void chol_kernel(const float* __restrict__ ztpiz,
                                                   const float* __restrict__ gram,
                                                   const int* __restrict__ counts,
                                                   float* __restrict__ ld, int m) {
  const int b = blockIdx.x;
  __shared__ float l11s[8][9];
  __shared__ float invd[8];
  __shared__ float diagv[D];
  __shared__ float panT[8][132];
  __shared__ float red[128];

  const int tid = threadIdx.x;

  // ---- compact map: tid -> lower tile (trb, tcb); 272 valid tiles ----
  int tcb = 0, trb = 0;
  bool valid = false;
  {
    int cum = 0;
    for (int c = 0; c < 16; ++c) {
      const int cnt = 32 - 2 * c;
      if (tid >= cum && tid < cum + cnt) {
        tcb = c;
        trb = 2 * c + (tid - cum);
        valid = true;
      }
      cum += cnt;
    }
  }
  const int R = trb * 4, C = tcb * 8;

  const float* src;
  float sc;
  if (b == 0) {
    src = gram;
    sc = (float)D / ((float)m * EPSv);
  } else {
    src = ztpiz + (size_t)(b - 1) * D * D;
    const float cf = (float)counts[b - 1] + 1e-8f;
    sc = (float)D / (cf * EPSv);
  }

  float a[4][8];
  if (valid) {
#pragma unroll
    for (int i = 0; i < 4; ++i) {
      const float* sp = src + (size_t)(R + i) * D + C;
      float tv[8];
      *(float4*)&tv[0] = *(const float4*)sp;
      *(float4*)&tv[4] = *(const float4*)(sp + 4);
#pragma unroll
      for (int j = 0; j < 8; ++j)
        a[i][j] = sc * tv[j] + ((R + i) == (C + j) ? 1.0f : 0.0f);
    }
  }

// 2-lane cooperative 8x8 factor of the diag block held by threads
// (trb even, trb+1) in their a[4][8] registers; publishes l11s/invd/diagv.
// All register indices static (kk, j, i unrolled); lane indices runtime.
#define FACTOR2_PUBLISH(DROW)                                               \
  {                                                                         \
    const int myh = trb & 1;                                                \
    const int l0 = (tid - myh) & 63;                                        \
    float dr[8], lk[8];                                                     \
    _Pragma("unroll")                                                       \
    for (int kk = 0; kk < 8; ++kk) {                                        \
      const float xkk = __shfl(a[kk & 3][kk], l0 + (kk >> 2));              \
      const float rk = rsqrtf(xkk);                                         \
      dr[kk] = rk; lk[kk] = xkk * rk;                                       \
      _Pragma("unroll")                                                     \
      for (int i = 0; i < 4; ++i) {                                         \
        const int gi = 4 * myh + i;                                         \
        if (gi > kk) a[i][kk] *= rk;                                        \
        else if (gi == kk) a[i][kk] = lk[kk];                               \
      }                                                                     \
      _Pragma("unroll")                                                     \
      for (int j = kk + 1; j < 8; ++j) {                                    \
        const float cj = __shfl(a[j & 3][kk], l0 + (j >> 2));               \
        _Pragma("unroll")                                                   \
        for (int i = 0; i < 4; ++i) {                                       \
          const int gi = 4 * myh + i;                                       \
          if (gi >= j) a[i][j] = fmaf(-a[i][kk], cj, a[i][j]);              \
        }                                                                   \
      }                                                                     \
    }                                                                       \
    _Pragma("unroll")                                                       \
    for (int i = 0; i < 4; ++i) {                                           \
      const int gr = 4 * myh + i;                                           \
      _Pragma("unroll")                                                     \
      for (int j = 0; j < 8; ++j) l11s[gr][j] = a[i][j];                    \
    }                                                                       \
    if (myh == 0) {                                                         \
      _Pragma("unroll")                                                     \
      for (int kk = 0; kk < 8; ++kk) {                                      \
        invd[kk] = dr[kk];                                                  \
        diagv[(DROW) + kk] = lk[kk];                                        \
      }                                                                     \
    }                                                                       \
  }

  // ---- prologue: factor diag block 0 (threads with tcb=0, trb=0/1) ----
  if (valid && tcb == 0 && trb <= 1) FACTOR2_PUBLISH(0);
  __syncthreads();

  for (int ct = 0; ct < 15; ++ct) {
    // --- phase A: panel solve (col-block ct, rows below the diag block) ---
    if (valid && tcb == ct && trb >= 2 * ct + 2) {
#pragma unroll
      for (int j = 0; j < 8; ++j) {
#pragma unroll
        for (int i = 0; i < 4; ++i) {
          float x = a[i][j];
#pragma unroll
          for (int q = 0; q < 8; ++q)
            if (q < j) x = fmaf(-a[i][q], l11s[j][q], x);
          a[i][j] = x * invd[j];
        }
      }
#pragma unroll
      for (int pq = 0; pq < 8; ++pq) {
        float t4[4];
#pragma unroll
        for (int i = 0; i < 4; ++i) t4[i] = a[i][pq];
        *(float4*)&panT[pq][R] = *(float4*)&t4[0];
      }
    }
    __syncthreads();

    // --- phase B: rank-8 trailing; next-diag owners then factor in-reg ---
    if (valid && tcb >= ct + 1) {
#pragma unroll 4
      for (int pq = 0; pq < 8; ++pq) {
        float cr4[4], cc8[8];
        *(float4*)&cr4[0] = *(const float4*)&panT[pq][R];
        *(float4*)&cc8[0] = *(const float4*)&panT[pq][C];
        *(float4*)&cc8[4] = *(const float4*)&panT[pq][C + 4];
#pragma unroll
        for (int i = 0; i < 4; ++i)
#pragma unroll
          for (int j = 0; j < 8; ++j)
            a[i][j] = fmaf(-cr4[i], cc8[j], a[i][j]);
      }
      if (tcb == ct + 1 && trb <= 2 * ct + 3) FACTOR2_PUBLISH(8 * (ct + 1));
    }
    __syncthreads();
  }

  // ---- logdet from diagv ----
  if (tid < 128) red[tid] = logf(diagv[tid]);
  __syncthreads();
  for (int off = 64; off > 0; off >>= 1) {
    if (tid < off) red[tid] += red[tid + off];
    __syncthreads();
  }
  if (tid == 0) ld[b] = 2.0f * red[0];
}

// ---------------------------------------------------------------------------
// Loss scalar only. One wave.
// ---------------------------------------------------------------------------
__global__ void finalize_kernel(const float* __restrict__ ldv,
                                const int* __restrict__ counts,
                                float* __restrict__ out, int m) {
  const int lane = threadIdx.x & 63;
  float v = 0.f;
  if (lane < K_CLASSES)
    v = ldv[lane + 1] * (((float)counts[lane] + 1e-8f) / (float)m);
#pragma unroll
  for (int off = 32; off > 0; off >>= 1) v += __shfl_down(v, off);
  if (lane == 0) out[0] = -0.5f * ldv[0] + 0.5f * v;
}

extern "C" void kernel_launch(void* const* d_in, const int* in_sizes, int n_in,
                              void* d_out, int out_size, void* d_ws, size_t ws_size,
                              hipStream_t stream) {
  const float* Z = (const float*)d_in[0];
  const int* Y = (const int*)d_in[1];
  float* out = (float*)d_out;
  const int m = in_sizes[0] / D;

  float* ztpiz = out + 1;  // (K, D, D)

  const size_t perChunk = (size_t)K_CLASSES * D * D * sizeof(float);  // 2 MB
  int nchunk = 32;
  for (;; nchunk >>= 1) {
    const size_t need = (size_t)nchunk * perChunk +
                        (size_t)nchunk * K_CLASSES * (D + 1) * sizeof(float) +
                        K_CLASSES * sizeof(int) + 64 * 1024 + 4096;
    if (nchunk == 1 || need <= ws_size) break;
  }

  char* wsb = (char*)d_ws;
  float* part = (nchunk == 1) ? ztpiz : (float*)wsb;
  size_t off = (nchunk == 1) ? 0 : (size_t)nchunk * perChunk;
  float* percls_part = (float*)(wsb + off); off += (size_t)nchunk * K_CLASSES * D * sizeof(float);
  int* counts_part = (int*)(wsb + off);     off += (size_t)nchunk * K_CLASSES * sizeof(int);
  int* counts_total = (int*)(wsb + off);    off += K_CLASSES * sizeof(int);
  float* ld = (float*)(wsb + off);          off += 64 * sizeof(float);
  float* gram = (float*)(wsb + ((off + 255) & ~(size_t)255));

  const int chunkRows = (m + nchunk - 1) / nchunk;

  class_gram_kernel<<<dim3(nchunk, K_CLASSES), 256, 0, stream>>>(
      Z, Y, part, counts_part, percls_part, m, chunkRows);
  reduce1_kernel<<<dim3(16, K_CLASSES), 256, 0, stream>>>(
      (const float4*)part, (float4*)ztpiz, nchunk);
  reduce2_kernel<<<65, 256, 0, stream>>>(ztpiz, gram, counts_part, counts_total,
                                         percls_part, out + 1 + K_CLASSES * D * D,
                                         nchunk, m);
  chol_kernel<<<K_CLASSES + 1, 512, 0, stream>>>(ztpiz, gram, counts_total, ld, m);
  finalize_kernel<<<1, 64, 0, stream>>>(ld, counts_total, out, m);
}

// Round 16
// 104.140 us; speedup vs baseline: 1.2705x; 1.2705x over previous
//
#include <hip/hip_runtime.h>

#define K_CLASSES 32
#define D 128
#define EPSv 0.5f
#define ZPAD 42   // shorts per row: 21 dwords, coprime with 32 banks
#define WIN 4096  // window rows per list build (list LDS capacity)

typedef __attribute__((ext_vector_type(8))) short short8;
typedef __attribute__((ext_vector_type(4))) float f32x4;

// fp32 -> bf16 round-to-nearest-even
static __device__ inline unsigned short f2bf(float f) {
  union { float f; unsigned u; } x; x.f = f;
  unsigned r = x.u + 0x7FFFu + ((x.u >> 16) & 1u);
  return (unsigned short)(r >> 16);
}
static __device__ inline float bf2f(unsigned short h) {
  union { unsigned u; float f; } x;
  x.u = (unsigned)h << 16;
  return x.f;
}

// ---------------------------------------------------------------------------
// Partial per-class Gram via bf16 MFMA. Accumulates fp32 in registers;
// writes partials as BF16 (halves reduce-stage HBM traffic; error ~0.2%
// per partial, far under the 46.4 threshold).
// ---------------------------------------------------------------------------
__global__ __launch_bounds__(256) void class_gram_kernel(
    const float* __restrict__ Z, const int* __restrict__ Y,
    unsigned short* __restrict__ part, int* __restrict__ counts_part,
    float* __restrict__ percls_part, int m, int chunkRows) {
  const int k = blockIdx.y;
  const int c = blockIdx.x;
  const int tid = threadIdx.x;
  const int lane = tid & 63;
  const int w = tid >> 6;

  const int rowStart = c * chunkRows;
  const int rowEnd = min(m, rowStart + chunkRows);

  __shared__ int list[WIN];
  __shared__ unsigned short zs[128][ZPAD];
  __shared__ int wsum[4];

  const int p = tid >> 4;
  const int part16 = tid & 15;
  const int l15 = lane & 15;
  const int kb = (lane >> 4) * 8;
  const int rb0 = w * 2, rb1 = w * 2 + 1;

  f32x4 acc0[8], acc1[8];
#pragma unroll
  for (int cb = 0; cb < 8; ++cb) { acc0[cb] = (f32x4)(0.f); acc1[cb] = (f32x4)(0.f); }
  float colacc[8];
#pragma unroll
  for (int j = 0; j < 8; ++j) colacc[j] = 0.f;

  int matched = 0;

#define LOAD_STAGE(d0, d1, stidx)                                   \
  {                                                                 \
    _Pragma("unroll") for (int j = 0; j < 8; ++j) { d0[j] = 0.f; d1[j] = 0.f; } \
    if ((stidx) < nst) {                                            \
      const int i0 = ((stidx) << 5) + p * 2;                        \
      const int r0 = list[i0];                                      \
      const int r1 = list[i0 + 1];                                  \
      if (r0 >= 0) {                                                \
        const float* zp = Z + (size_t)r0 * D + part16 * 8;          \
        *(float4*)&d0[0] = *(const float4*)zp;                      \
        *(float4*)&d0[4] = *(const float4*)(zp + 4);                \
      }                                                             \
      if (r1 >= 0) {                                                \
        const float* zp = Z + (size_t)r1 * D + part16 * 8;          \
        *(float4*)&d1[0] = *(const float4*)zp;                      \
        *(float4*)&d1[4] = *(const float4*)(zp + 4);                \
      }                                                             \
    }                                                               \
  }

#define STAGE_BODY(s0, s1)                                          \
  {                                                                 \
    _Pragma("unroll") for (int j = 0; j < 8; ++j) colacc[j] += s0[j] + s1[j]; \
    __syncthreads();                                                \
    _Pragma("unroll") for (int j = 0; j < 8; ++j) {                 \
      const unsigned pk = (unsigned)f2bf(s0[j]) | ((unsigned)f2bf(s1[j]) << 16); \
      *(unsigned*)&zs[part16 * 8 + j][2 * p] = pk;                  \
    }                                                               \
    __syncthreads();                                                \
  }

#define MFMA_BODY()                                                 \
  {                                                                 \
    short8 fragC[8];                                                \
    _Pragma("unroll") for (int fb = 0; fb < 8; ++fb)                \
      fragC[fb] = *(const short8*)&zs[fb * 16 + l15][kb];           \
    const short8 fragR0 = *(const short8*)&zs[rb0 * 16 + l15][kb];  \
    const short8 fragR1 = *(const short8*)&zs[rb1 * 16 + l15][kb];  \
    _Pragma("unroll") for (int cb = 0; cb < 8; ++cb) {              \
      acc0[cb] = __builtin_amdgcn_mfma_f32_16x16x32_bf16(fragR0, fragC[cb], acc0[cb], 0, 0, 0); \
      acc1[cb] = __builtin_amdgcn_mfma_f32_16x16x32_bf16(fragR1, fragC[cb], acc1[cb], 0, 0, 0); \
    }                                                               \
  }

  for (int w0 = rowStart; w0 < rowEnd; w0 += WIN) {
    const int wend = min(w0 + WIN, rowEnd);
    __syncthreads();

    int run = 0;
    for (int base = w0; base < wend; base += 2048) {
      const int start = base + tid * 8;
      int yv[8];
      if (((start & 3) == 0) && start + 8 <= wend) {
        const int4 ya = *(const int4*)(Y + start);
        const int4 yb = *(const int4*)(Y + start + 4);
        yv[0] = ya.x; yv[1] = ya.y; yv[2] = ya.z; yv[3] = ya.w;
        yv[4] = yb.x; yv[5] = yb.y; yv[6] = yb.z; yv[7] = yb.w;
      } else {
#pragma unroll
        for (int e = 0; e < 8; ++e) {
          const int r = start + e;
          yv[e] = (r < wend) ? Y[r] : -1;
        }
      }
      int cnt = 0;
#pragma unroll
      for (int e = 0; e < 8; ++e) cnt += (yv[e] == k) ? 1 : 0;
      int cs = cnt;
#pragma unroll
      for (int off = 1; off < 64; off <<= 1) {
        const int nbr = __shfl_up(cs, off);
        if (lane >= off) cs += nbr;
      }
      if (lane == 63) wsum[w] = cs;
      const int excl = cs - cnt;
      __syncthreads();
      int woff = 0, ctot = 0;
#pragma unroll
      for (int ww = 0; ww < 4; ++ww) {
        const int v = wsum[ww];
        if (ww < w) woff += v;
        ctot += v;
      }
      __syncthreads();
      int pos = run + woff + excl;
#pragma unroll
      for (int e = 0; e < 8; ++e) {
        if (yv[e] == k) { list[pos] = start + e; ++pos; }
      }
      run += ctot;
    }
    const int total = run;
    matched += total;
    const int padded = (total + 31) & ~31;
    for (int i = total + tid; i < padded; i += 256) list[i] = -1;
    __syncthreads();

    const int nst = padded >> 5;
    float vA0[8], vA1[8], vB0[8], vB1[8];
    LOAD_STAGE(vA0, vA1, 0);
    LOAD_STAGE(vB0, vB1, 1);

    for (int st = 0; st < nst; st += 2) {
      STAGE_BODY(vA0, vA1);
      LOAD_STAGE(vA0, vA1, st + 2);
      MFMA_BODY();
      if (st + 1 < nst) {
        STAGE_BODY(vB0, vB1);
        LOAD_STAGE(vB0, vB1, st + 3);
        MFMA_BODY();
      }
    }
  }

  // ---- write partial Gram as bf16 (owner writes, no atomics) ----
  unsigned short* dst = part + ((size_t)c * K_CLASSES + k) * (D * D);
  const int l4 = lane >> 4;
#pragma unroll
  for (int cb = 0; cb < 8; ++cb)
#pragma unroll
    for (int q = 0; q < 4; ++q) {
      dst[(rb0 * 16 + l4 * 4 + q) * D + cb * 16 + l15] = f2bf(acc0[cb][q]);
      dst[(rb1 * 16 + l4 * 4 + q) * D + cb * 16 + l15] = f2bf(acc1[cb][q]);
    }

  __syncthreads();
  float* cred = (float*)&zs[0][0];
#pragma unroll
  for (int j = 0; j < 8; ++j) cred[p * 128 + part16 * 8 + j] = colacc[j];
  __syncthreads();
  if (tid < 128) {
    float s = 0.f;
#pragma unroll
    for (int pp = 0; pp < 16; ++pp) s += cred[pp * 128 + tid];
    percls_part[(c * K_CLASSES + k) * D + tid] = s;
  }
  if (tid == 0) counts_part[c * K_CLASSES + k] = matched;
}

// ---------------------------------------------------------------------------
// R1: ztpiz[k][e] = sum_c bf2f(part[c][k][e]). Grid (16, K), 4 elems/thread.
// Deterministic fixed-order sum in fp32.
// ---------------------------------------------------------------------------
__global__ __launch_bounds__(256) void reduce1_kernel(
    const unsigned short* __restrict__ part, float4* __restrict__ ztpiz,
    int nchunk) {
  const int k = blockIdx.y;
  const int e4 = blockIdx.x * 256 + threadIdx.x;  // float4 index, D*D/4 = 4096
  float4 s = make_float4(0.f, 0.f, 0.f, 0.f);
  for (int c = 0; c < nchunk; ++c) {
    const ushort4 v = *(const ushort4*)(part +
        ((size_t)c * K_CLASSES + k) * (D * D) + (size_t)e4 * 4);
    s.x += bf2f(v.x); s.y += bf2f(v.y); s.z += bf2f(v.z); s.w += bf2f(v.w);
  }
  ztpiz[(size_t)k * (D * D / 4) + e4] = s;
}

// ---------------------------------------------------------------------------
// R2: blocks 0..63: gram[e] = sum_k ztpiz[k][e] (parallel, L2-hot).
//     block 64: Z_mean -> out (8 accumulator chains), counts_total.
// ---------------------------------------------------------------------------
__global__ __launch_bounds__(256) void reduce2_kernel(
    const float* __restrict__ ztpiz, float* __restrict__ gram,
    const int* __restrict__ counts_part, int* __restrict__ counts_total,
    const float* __restrict__ percls_part, float* __restrict__ zmean_out,
    int nchunk, int m) {
  if (blockIdx.x < 64) {
    const int e = blockIdx.x * 256 + threadIdx.x;
    float g = 0.f;
#pragma unroll
    for (int k = 0; k < K_CLASSES; ++k) g += ztpiz[(size_t)k * D * D + e];
    gram[e] = g;
  } else {
    __shared__ float buf[256];
    const int col = threadIdx.x & 127;
    const int half = threadIdx.x >> 7;
    const int np = nchunk * K_CLASSES;
    float s0 = 0.f, s1 = 0.f, s2 = 0.f, s3 = 0.f;
    float s4 = 0.f, s5 = 0.f, s6 = 0.f, s7 = 0.f;
    int i = half;
    for (; i + 14 < np; i += 16) {
      s0 += percls_part[(i)*D + col];
      s1 += percls_part[(i + 2) * D + col];
      s2 += percls_part[(i + 4) * D + col];
      s3 += percls_part[(i + 6) * D + col];
      s4 += percls_part[(i + 8) * D + col];
      s5 += percls_part[(i + 10) * D + col];
      s6 += percls_part[(i + 12) * D + col];
      s7 += percls_part[(i + 14) * D + col];
    }
    for (; i < np; i += 2) s0 += percls_part[i * D + col];
    buf[threadIdx.x] = ((s0 + s1) + (s2 + s3)) + ((s4 + s5) + (s6 + s7));
    __syncthreads();
    if (threadIdx.x < 128)
      zmean_out[threadIdx.x] = (buf[threadIdx.x] + buf[threadIdx.x + 128]) / (float)m;
    if (threadIdx.x < K_CLASSES) {
      int t = 0;
      for (int c = 0; c < nchunk; ++c) t += counts_part[c * K_CLASSES + threadIdx.x];
      counts_total[threadIdx.x] = t;
    }
  }
}

// ---------------------------------------------------------------------------
// Blocked Cholesky of I + s*G (EXACT round-13 version, measured 42.0 us):
// 512 threads, compact lower-triangle 4x8 tile map (272 tiles), 8-lane
// shuffle diag factor, 3 barriers per rank-8 step. r14 (rank-16) and r15
// (embedded 2-lane factor) both regressed -- this structure is the floor.
// ---------------------------------------------------------------------------
__global__ __launch_bounds__(512) void chol_kernel(const float* __restrict__ ztpiz,
                                                   const float* __restrict__ gram,
                                                   const int* __restrict__ counts,
                                                   float* __restrict__ ld, int m) {
  const int b = blockIdx.x;
  __shared__ float diag8[8][8];
  __shared__ float l11s[8][9];
  __shared__ float invd[8];
  __shared__ float diagv[D];
  __shared__ float panT[8][132];
  __shared__ float red[128];

  const int tid = threadIdx.x;

  int tcb = 0, trb = 0;
  bool valid = false;
  {
    int cum = 0;
    for (int c = 0; c < 16; ++c) {
      const int cnt = 32 - 2 * c;
      if (tid >= cum && tid < cum + cnt) {
        tcb = c;
        trb = 2 * c + (tid - cum);
        valid = true;
      }
      cum += cnt;
    }
  }
  const int R = trb * 4, C = tcb * 8;

  const float* src;
  float sc;
  if (b == 0) {
    src = gram;
    sc = (float)D / ((float)m * EPSv);
  } else {
    src = ztpiz + (size_t)(b - 1) * D * D;
    const float cf = (float)counts[b - 1] + 1e-8f;
    sc = (float)D / (cf * EPSv);
  }

  float a[4][8];
  if (valid) {
#pragma unroll
    for (int i = 0; i < 4; ++i) {
      const float* sp = src + (size_t)(R + i) * D + C;
      float tv[8];
      *(float4*)&tv[0] = *(const float4*)sp;
      *(float4*)&tv[4] = *(const float4*)(sp + 4);
#pragma unroll
      for (int j = 0; j < 8; ++j)
        a[i][j] = sc * tv[j] + ((R + i) == (C + j) ? 1.0f : 0.0f);
    }
  }

  if (valid && tcb == 0 && trb <= 1) {
    const int hb = trb * 4;
#pragma unroll
    for (int i = 0; i < 4; ++i) {
      *(float4*)&diag8[hb + i][0] = *(float4*)&a[i][0];
      *(float4*)&diag8[hb + i][4] = *(float4*)&a[i][4];
    }
  }
  __syncthreads();

  for (int ct = 0; ct < 16; ++ct) {
    if (tid < 8) {
      const int r = tid;
      float v[8];
      *(float4*)&v[0] = *(float4*)&diag8[r][0];
      *(float4*)&v[4] = *(float4*)&diag8[r][4];
      float myinv = 0.f, mydiag = 1.f;
#pragma unroll
      for (int kk = 0; kk < 8; ++kk) {
        const float xkk = __shfl(v[kk], kk);
        const float rk = rsqrtf(xkk);
        v[kk] *= rk;
        if (r == kk) { myinv = rk; mydiag = v[kk]; }
#pragma unroll
        for (int j = kk + 1; j < 8; ++j) {
          const float cj = __shfl(v[kk], j);
          if (r >= j) v[j] = fmaf(-v[kk], cj, v[j]);
        }
      }
#pragma unroll
      for (int j = 0; j < 8; ++j) l11s[r][j] = v[j];
      invd[r] = myinv;
      diagv[8 * ct + r] = mydiag;
    }
    __syncthreads();

    if (valid && tcb == ct && trb >= 2 * ct + 2) {
#pragma unroll
      for (int j = 0; j < 8; ++j) {
#pragma unroll
        for (int i = 0; i < 4; ++i) {
          float x = a[i][j];
#pragma unroll
          for (int q = 0; q < 8; ++q)
            if (q < j) x = fmaf(-a[i][q], l11s[j][q], x);
          a[i][j] = x * invd[j];
        }
      }
#pragma unroll
      for (int pq = 0; pq < 8; ++pq) {
        float t4[4];
#pragma unroll
        for (int i = 0; i < 4; ++i) t4[i] = a[i][pq];
        *(float4*)&panT[pq][R] = *(float4*)&t4[0];
      }
    }
    __syncthreads();

    if (valid && tcb >= ct + 1) {
#pragma unroll 4
      for (int pq = 0; pq < 8; ++pq) {
        float cr4[4], cc8[8];
        *(float4*)&cr4[0] = *(const float4*)&panT[pq][R];
        *(float4*)&cc8[0] = *(const float4*)&panT[pq][C];
        *(float4*)&cc8[4] = *(const float4*)&panT[pq][C + 4];
#pragma unroll
        for (int i = 0; i < 4; ++i)
#pragma unroll
          for (int j = 0; j < 8; ++j)
            a[i][j] = fmaf(-cr4[i], cc8[j], a[i][j]);
      }
      if (tcb == ct + 1 && trb <= 2 * ct + 3) {
        const int hb = (trb - 2 * (ct + 1)) * 4;
#pragma unroll
        for (int i = 0; i < 4; ++i) {
          *(float4*)&diag8[hb + i][0] = *(float4*)&a[i][0];
          *(float4*)&diag8[hb + i][4] = *(float4*)&a[i][4];
        }
      }
    }
    __syncthreads();
  }

  if (tid < 128) red[tid] = logf(diagv[tid]);
  __syncthreads();
  for (int off = 64; off > 0; off >>= 1) {
    if (tid < off) red[tid] += red[tid + off];
    __syncthreads();
  }
  if (tid == 0) ld[b] = 2.0f * red[0];
}

// ---------------------------------------------------------------------------
// Loss scalar only. One wave.
// ---------------------------------------------------------------------------
__global__ void finalize_kernel(const float* __restrict__ ldv,
                                const int* __restrict__ counts,
                                float* __restrict__ out, int m) {
  const int lane = threadIdx.x & 63;
  float v = 0.f;
  if (lane < K_CLASSES)
    v = ldv[lane + 1] * (((float)counts[lane] + 1e-8f) / (float)m);
#pragma unroll
  for (int off = 32; off > 0; off >>= 1) v += __shfl_down(v, off);
  if (lane == 0) out[0] = -0.5f * ldv[0] + 0.5f * v;
}

extern "C" void kernel_launch(void* const* d_in, const int* in_sizes, int n_in,
                              void* d_out, int out_size, void* d_ws, size_t ws_size,
                              hipStream_t stream) {
  const float* Z = (const float*)d_in[0];
  const int* Y = (const int*)d_in[1];
  float* out = (float*)d_out;
  const int m = in_sizes[0] / D;

  float* ztpiz = out + 1;  // (K, D, D)

  // bf16 partials: 1 MB per chunk
  const size_t perChunk = (size_t)K_CLASSES * D * D * sizeof(unsigned short);
  int nchunk = 32;
  for (;; nchunk >>= 1) {
    const size_t need = (size_t)nchunk * perChunk +
                        (size_t)nchunk * K_CLASSES * (D + 1) * sizeof(float) +
                        K_CLASSES * sizeof(int) + 64 * 1024 + 4096;
    if (nchunk == 1 || need <= ws_size) break;
  }

  char* wsb = (char*)d_ws;
  unsigned short* part = (unsigned short*)wsb;
  size_t off = (size_t)nchunk * perChunk;
  float* percls_part = (float*)(wsb + off); off += (size_t)nchunk * K_CLASSES * D * sizeof(float);
  int* counts_part = (int*)(wsb + off);     off += (size_t)nchunk * K_CLASSES * sizeof(int);
  int* counts_total = (int*)(wsb + off);    off += K_CLASSES * sizeof(int);
  float* ld = (float*)(wsb + off);          off += 64 * sizeof(float);
  float* gram = (float*)(wsb + ((off + 255) & ~(size_t)255));

  const int chunkRows = (m + nchunk - 1) / nchunk;

  class_gram_kernel<<<dim3(nchunk, K_CLASSES), 256, 0, stream>>>(
      Z, Y, part, counts_part, percls_part, m, chunkRows);
  reduce1_kernel<<<dim3(16, K_CLASSES), 256, 0, stream>>>(
      part, (float4*)ztpiz, nchunk);
  reduce2_kernel<<<65, 256, 0, stream>>>(ztpiz, gram, counts_part, counts_total,
                                         percls_part, out + 1 + K_CLASSES * D * D,
                                         nchunk, m);
  chol_kernel<<<K_CLASSES + 1, 512, 0, stream>>>(ztpiz, gram, counts_total, ld, m);
  finalize_kernel<<<1, 64, 0, stream>>>(ld, counts_total, out, m);
}

// Round 17
// 84.525 us; speedup vs baseline: 1.5653x; 1.2321x over previous
//
#include <hip/hip_runtime.h>

#define K_CLASSES 32
#define D 128
#define EPSv 0.5f
#define ZPAD 42   // shorts per row: 21 dwords, coprime with 32 banks
#define WIN 4096  // window rows per list build (list LDS capacity)

typedef __attribute__((ext_vector_type(8))) short short8;
typedef __attribute__((ext_vector_type(4))) float f32x4;

// fp32 -> bf16 round-to-nearest-even
static __device__ inline unsigned short f2bf(float f) {
  union { float f; unsigned u; } x; x.f = f;
  unsigned r = x.u + 0x7FFFu + ((x.u >> 16) & 1u);
  return (unsigned short)(r >> 16);
}
static __device__ inline float bf2f(unsigned short h) {
  union { unsigned u; float f; } x;
  x.u = (unsigned)h << 16;
  return x.f;
}

// ---------------------------------------------------------------------------
// Partial per-class Gram via bf16 MFMA. fp32 register accumulation; bf16
// partial writes. nchunk=16: one 4096-row window per block (list build
// amortized over 4 MFMA stages), partial traffic halved vs nchunk=32.
// ---------------------------------------------------------------------------
__global__ __launch_bounds__(256) void class_gram_kernel(
    const float* __restrict__ Z, const int* __restrict__ Y,
    unsigned short* __restrict__ part, int* __restrict__ counts_part,
    float* __restrict__ percls_part, int m, int chunkRows) {
  const int k = blockIdx.y;
  const int c = blockIdx.x;
  const int tid = threadIdx.x;
  const int lane = tid & 63;
  const int w = tid >> 6;

  const int rowStart = c * chunkRows;
  const int rowEnd = min(m, rowStart + chunkRows);

  __shared__ int list[WIN];
  __shared__ unsigned short zs[128][ZPAD];
  __shared__ int wsum[4];

  const int p = tid >> 4;
  const int part16 = tid & 15;
  const int l15 = lane & 15;
  const int kb = (lane >> 4) * 8;
  const int rb0 = w * 2, rb1 = w * 2 + 1;

  f32x4 acc0[8], acc1[8];
#pragma unroll
  for (int cb = 0; cb < 8; ++cb) { acc0[cb] = (f32x4)(0.f); acc1[cb] = (f32x4)(0.f); }
  float colacc[8];
#pragma unroll
  for (int j = 0; j < 8; ++j) colacc[j] = 0.f;

  int matched = 0;

#define LOAD_STAGE(d0, d1, stidx)                                   \
  {                                                                 \
    _Pragma("unroll") for (int j = 0; j < 8; ++j) { d0[j] = 0.f; d1[j] = 0.f; } \
    if ((stidx) < nst) {                                            \
      const int i0 = ((stidx) << 5) + p * 2;                        \
      const int r0 = list[i0];                                      \
      const int r1 = list[i0 + 1];                                  \
      if (r0 >= 0) {                                                \
        const float* zp = Z + (size_t)r0 * D + part16 * 8;          \
        *(float4*)&d0[0] = *(const float4*)zp;                      \
        *(float4*)&d0[4] = *(const float4*)(zp + 4);                \
      }                                                             \
      if (r1 >= 0) {                                                \
        const float* zp = Z + (size_t)r1 * D + part16 * 8;          \
        *(float4*)&d1[0] = *(const float4*)zp;                      \
        *(float4*)&d1[4] = *(const float4*)(zp + 4);                \
      }                                                             \
    }                                                               \
  }

#define STAGE_BODY(s0, s1)                                          \
  {                                                                 \
    _Pragma("unroll") for (int j = 0; j < 8; ++j) colacc[j] += s0[j] + s1[j]; \
    __syncthreads();                                                \
    _Pragma("unroll") for (int j = 0; j < 8; ++j) {                 \
      const unsigned pk = (unsigned)f2bf(s0[j]) | ((unsigned)f2bf(s1[j]) << 16); \
      *(unsigned*)&zs[part16 * 8 + j][2 * p] = pk;                  \
    }                                                               \
    __syncthreads();                                                \
  }

#define MFMA_BODY()                                                 \
  {                                                                 \
    short8 fragC[8];                                                \
    _Pragma("unroll") for (int fb = 0; fb < 8; ++fb)                \
      fragC[fb] = *(const short8*)&zs[fb * 16 + l15][kb];           \
    const short8 fragR0 = *(const short8*)&zs[rb0 * 16 + l15][kb];  \
    const short8 fragR1 = *(const short8*)&zs[rb1 * 16 + l15][kb];  \
    _Pragma("unroll") for (int cb = 0; cb < 8; ++cb) {              \
      acc0[cb] = __builtin_amdgcn_mfma_f32_16x16x32_bf16(fragR0, fragC[cb], acc0[cb], 0, 0, 0); \
      acc1[cb] = __builtin_amdgcn_mfma_f32_16x16x32_bf16(fragR1, fragC[cb], acc1[cb], 0, 0, 0); \
    }                                                               \
  }

  for (int w0 = rowStart; w0 < rowEnd; w0 += WIN) {
    const int wend = min(w0 + WIN, rowEnd);
    __syncthreads();

    int run = 0;
    for (int base = w0; base < wend; base += 2048) {
      const int start = base + tid * 8;
      int yv[8];
      if (((start & 3) == 0) && start + 8 <= wend) {
        const int4 ya = *(const int4*)(Y + start);
        const int4 yb = *(const int4*)(Y + start + 4);
        yv[0] = ya.x; yv[1] = ya.y; yv[2] = ya.z; yv[3] = ya.w;
        yv[4] = yb.x; yv[5] = yb.y; yv[6] = yb.z; yv[7] = yb.w;
      } else {
#pragma unroll
        for (int e = 0; e < 8; ++e) {
          const int r = start + e;
          yv[e] = (r < wend) ? Y[r] : -1;
        }
      }
      int cnt = 0;
#pragma unroll
      for (int e = 0; e < 8; ++e) cnt += (yv[e] == k) ? 1 : 0;
      int cs = cnt;
#pragma unroll
      for (int off = 1; off < 64; off <<= 1) {
        const int nbr = __shfl_up(cs, off);
        if (lane >= off) cs += nbr;
      }
      if (lane == 63) wsum[w] = cs;
      const int excl = cs - cnt;
      __syncthreads();
      int woff = 0, ctot = 0;
#pragma unroll
      for (int ww = 0; ww < 4; ++ww) {
        const int v = wsum[ww];
        if (ww < w) woff += v;
        ctot += v;
      }
      __syncthreads();
      int pos = run + woff + excl;
#pragma unroll
      for (int e = 0; e < 8; ++e) {
        if (yv[e] == k) { list[pos] = start + e; ++pos; }
      }
      run += ctot;
    }
    const int total = run;
    matched += total;
    const int padded = (total + 31) & ~31;
    for (int i = total + tid; i < padded; i += 256) list[i] = -1;
    __syncthreads();

    const int nst = padded >> 5;
    float vA0[8], vA1[8], vB0[8], vB1[8];
    LOAD_STAGE(vA0, vA1, 0);
    LOAD_STAGE(vB0, vB1, 1);

    for (int st = 0; st < nst; st += 2) {
      STAGE_BODY(vA0, vA1);
      LOAD_STAGE(vA0, vA1, st + 2);
      MFMA_BODY();
      if (st + 1 < nst) {
        STAGE_BODY(vB0, vB1);
        LOAD_STAGE(vB0, vB1, st + 3);
        MFMA_BODY();
      }
    }
  }

  // ---- write partial Gram as bf16 (owner writes, no atomics) ----
  unsigned short* dst = part + ((size_t)c * K_CLASSES + k) * (D * D);
  const int l4 = lane >> 4;
#pragma unroll
  for (int cb = 0; cb < 8; ++cb)
#pragma unroll
    for (int q = 0; q < 4; ++q) {
      dst[(rb0 * 16 + l4 * 4 + q) * D + cb * 16 + l15] = f2bf(acc0[cb][q]);
      dst[(rb1 * 16 + l4 * 4 + q) * D + cb * 16 + l15] = f2bf(acc1[cb][q]);
    }

  __syncthreads();
  float* cred = (float*)&zs[0][0];
#pragma unroll
  for (int j = 0; j < 8; ++j) cred[p * 128 + part16 * 8 + j] = colacc[j];
  __syncthreads();
  if (tid < 128) {
    float s = 0.f;
#pragma unroll
    for (int pp = 0; pp < 16; ++pp) s += cred[pp * 128 + tid];
    percls_part[(c * K_CLASSES + k) * D + tid] = s;
  }
  if (tid == 0) counts_part[c * K_CLASSES + k] = matched;
}

// ---------------------------------------------------------------------------
// R1: ztpiz[k][e] = sum_c bf2f(part[c][k][e]). Grid (16, K), 4 elems/thread.
// Deterministic fixed-order sum in fp32.
// ---------------------------------------------------------------------------
__global__ __launch_bounds__(256) void reduce1_kernel(
    const unsigned short* __restrict__ part, float4* __restrict__ ztpiz,
    int nchunk) {
  const int k = blockIdx.y;
  const int e4 = blockIdx.x * 256 + threadIdx.x;  // float4 index, D*D/4 = 4096
  float4 s = make_float4(0.f, 0.f, 0.f, 0.f);
  for (int c = 0; c < nchunk; ++c) {
    const ushort4 v = *(const ushort4*)(part +
        ((size_t)c * K_CLASSES + k) * (D * D) + (size_t)e4 * 4);
    s.x += bf2f(v.x); s.y += bf2f(v.y); s.z += bf2f(v.z); s.w += bf2f(v.w);
  }
  ztpiz[(size_t)k * (D * D / 4) + e4] = s;
}

// ---------------------------------------------------------------------------
// R2: blocks 0..63: gram[e] = sum_k ztpiz[k][e] (parallel, L2-hot).
//     block 64: Z_mean -> out (8 accumulator chains), counts_total.
// ---------------------------------------------------------------------------
__global__ __launch_bounds__(256) void reduce2_kernel(
    const float* __restrict__ ztpiz, float* __restrict__ gram,
    const int* __restrict__ counts_part, int* __restrict__ counts_total,
    const float* __restrict__ percls_part, float* __restrict__ zmean_out,
    int nchunk, int m) {
  if (blockIdx.x < 64) {
    const int e = blockIdx.x * 256 + threadIdx.x;
    float g = 0.f;
#pragma unroll
    for (int k = 0; k < K_CLASSES; ++k) g += ztpiz[(size_t)k * D * D + e];
    gram[e] = g;
  } else {
    __shared__ float buf[256];
    const int col = threadIdx.x & 127;
    const int half = threadIdx.x >> 7;
    const int np = nchunk * K_CLASSES;
    float s0 = 0.f, s1 = 0.f, s2 = 0.f, s3 = 0.f;
    float s4 = 0.f, s5 = 0.f, s6 = 0.f, s7 = 0.f;
    int i = half;
    for (; i + 14 < np; i += 16) {
      s0 += percls_part[(i)*D + col];
      s1 += percls_part[(i + 2) * D + col];
      s2 += percls_part[(i + 4) * D + col];
      s3 += percls_part[(i + 6) * D + col];
      s4 += percls_part[(i + 8) * D + col];
      s5 += percls_part[(i + 10) * D + col];
      s6 += percls_part[(i + 12) * D + col];
      s7 += percls_part[(i + 14) * D + col];
    }
    for (; i < np; i += 2) s0 += percls_part[i * D + col];
    buf[threadIdx.x] = ((s0 + s1) + (s2 + s3)) + ((s4 + s5) + (s6 + s7));
    __syncthreads();
    if (threadIdx.x < 128)
      zmean_out[threadIdx.x] = (buf[threadIdx.x] + buf[threadIdx.x + 128]) / (float)m;
    if (threadIdx.x < K_CLASSES) {
      int t = 0;
      for (int c = 0; c < nchunk; ++c) t += counts_part[c * K_CLASSES + threadIdx.x];
      counts_total[threadIdx.x] = t;
    }
  }
}

// ---------------------------------------------------------------------------
// Blocked Cholesky of I + s*G (round-13 structure, measured 42.0 us floor):
// 512 threads, compact lower-triangle 4x8 tile map (272 tiles), 8-lane
// shuffle diag factor, 3 barriers per rank-8 step. DO NOT restructure:
// r14 (rank-16) and r15 (embedded factor) both regressed.
// ---------------------------------------------------------------------------
__global__ __launch_bounds__(512) void chol_kernel(const float* __restrict__ ztpiz,
                                                   const float* __restrict__ gram,
                                                   const int* __restrict__ counts,
                                                   float* __restrict__ ld, int m) {
  const int b = blockIdx.x;
  __shared__ float diag8[8][8];
  __shared__ float l11s[8][9];
  __shared__ float invd[8];
  __shared__ float diagv[D];
  __shared__ float panT[8][132];
  __shared__ float red[128];

  const int tid = threadIdx.x;

  int tcb = 0, trb = 0;
  bool valid = false;
  {
    int cum = 0;
    for (int c = 0; c < 16; ++c) {
      const int cnt = 32 - 2 * c;
      if (tid >= cum && tid < cum + cnt) {
        tcb = c;
        trb = 2 * c + (tid - cum);
        valid = true;
      }
      cum += cnt;
    }
  }
  const int R = trb * 4, C = tcb * 8;

  const float* src;
  float sc;
  if (b == 0) {
    src = gram;
    sc = (float)D / ((float)m * EPSv);
  } else {
    src = ztpiz + (size_t)(b - 1) * D * D;
    const float cf = (float)counts[b - 1] + 1e-8f;
    sc = (float)D / (cf * EPSv);
  }

  float a[4][8];
  if (valid) {
#pragma unroll
    for (int i = 0; i < 4; ++i) {
      const float* sp = src + (size_t)(R + i) * D + C;
      float tv[8];
      *(float4*)&tv[0] = *(const float4*)sp;
      *(float4*)&tv[4] = *(const float4*)(sp + 4);
#pragma unroll
      for (int j = 0; j < 8; ++j)
        a[i][j] = sc * tv[j] + ((R + i) == (C + j) ? 1.0f : 0.0f);
    }
  }

  if (valid && tcb == 0 && trb <= 1) {
    const int hb = trb * 4;
#pragma unroll
    for (int i = 0; i < 4; ++i) {
      *(float4*)&diag8[hb + i][0] = *(float4*)&a[i][0];
      *(float4*)&diag8[hb + i][4] = *(float4*)&a[i][4];
    }
  }
  __syncthreads();

  for (int ct = 0; ct < 16; ++ct) {
    if (tid < 8) {
      const int r = tid;
      float v[8];
      *(float4*)&v[0] = *(float4*)&diag8[r][0];
      *(float4*)&v[4] = *(float4*)&diag8[r][4];
      float myinv = 0.f, mydiag = 1.f;
#pragma unroll
      for (int kk = 0; kk < 8; ++kk) {
        const float xkk = __shfl(v[kk], kk);
        const float rk = rsqrtf(xkk);
        v[kk] *= rk;
        if (r == kk) { myinv = rk; mydiag = v[kk]; }
#pragma unroll
        for (int j = kk + 1; j < 8; ++j) {
          const float cj = __shfl(v[kk], j);
          if (r >= j) v[j] = fmaf(-v[kk], cj, v[j]);
        }
      }
#pragma unroll
      for (int j = 0; j < 8; ++j) l11s[r][j] = v[j];
      invd[r] = myinv;
      diagv[8 * ct + r] = mydiag;
    }
    __syncthreads();

    if (valid && tcb == ct && trb >= 2 * ct + 2) {
#pragma unroll
      for (int j = 0; j < 8; ++j) {
#pragma unroll
        for (int i = 0; i < 4; ++i) {
          float x = a[i][j];
#pragma unroll
          for (int q = 0; q < 8; ++q)
            if (q < j) x = fmaf(-a[i][q], l11s[j][q], x);
          a[i][j] = x * invd[j];
        }
      }
#pragma unroll
      for (int pq = 0; pq < 8; ++pq) {
        float t4[4];
#pragma unroll
        for (int i = 0; i < 4; ++i) t4[i] = a[i][pq];
        *(float4*)&panT[pq][R] = *(float4*)&t4[0];
      }
    }
    __syncthreads();

    if (valid && tcb >= ct + 1) {
#pragma unroll 4
      for (int pq = 0; pq < 8; ++pq) {
        float cr4[4], cc8[8];
        *(float4*)&cr4[0] = *(const float4*)&panT[pq][R];
        *(float4*)&cc8[0] = *(const float4*)&panT[pq][C];
        *(float4*)&cc8[4] = *(const float4*)&panT[pq][C + 4];
#pragma unroll
        for (int i = 0; i < 4; ++i)
#pragma unroll
          for (int j = 0; j < 8; ++j)
            a[i][j] = fmaf(-cr4[i], cc8[j], a[i][j]);
      }
      if (tcb == ct + 1 && trb <= 2 * ct + 3) {
        const int hb = (trb - 2 * (ct + 1)) * 4;
#pragma unroll
        for (int i = 0; i < 4; ++i) {
          *(float4*)&diag8[hb + i][0] = *(float4*)&a[i][0];
          *(float4*)&diag8[hb + i][4] = *(float4*)&a[i][4];
        }
      }
    }
    __syncthreads();
  }

  if (tid < 128) red[tid] = logf(diagv[tid]);
  __syncthreads();
  for (int off = 64; off > 0; off >>= 1) {
    if (tid < off) red[tid] += red[tid + off];
    __syncthreads();
  }
  if (tid == 0) ld[b] = 2.0f * red[0];
}

// ---------------------------------------------------------------------------
// Loss scalar only. One wave.
// ---------------------------------------------------------------------------
__global__ void finalize_kernel(const float* __restrict__ ldv,
                                const int* __restrict__ counts,
                                float* __restrict__ out, int m) {
  const int lane = threadIdx.x & 63;
  float v = 0.f;
  if (lane < K_CLASSES)
    v = ldv[lane + 1] * (((float)counts[lane] + 1e-8f) / (float)m);
#pragma unroll
  for (int off = 32; off > 0; off >>= 1) v += __shfl_down(v, off);
  if (lane == 0) out[0] = -0.5f * ldv[0] + 0.5f * v;
}

extern "C" void kernel_launch(void* const* d_in, const int* in_sizes, int n_in,
                              void* d_out, int out_size, void* d_ws, size_t ws_size,
                              hipStream_t stream) {
  const float* Z = (const float*)d_in[0];
  const int* Y = (const int*)d_in[1];
  float* out = (float*)d_out;
  const int m = in_sizes[0] / D;

  float* ztpiz = out + 1;  // (K, D, D)

  // bf16 partials: 1 MB per chunk. nchunk=16 (r17): halves partial traffic
  // vs 32 and doubles per-block stage count (list-build amortization).
  const size_t perChunk = (size_t)K_CLASSES * D * D * sizeof(unsigned short);
  int nchunk = 16;
  for (;; nchunk >>= 1) {
    const size_t need = (size_t)nchunk * perChunk +
                        (size_t)nchunk * K_CLASSES * (D + 1) * sizeof(float) +
                        K_CLASSES * sizeof(int) + 64 * 1024 + 4096;
    if (nchunk == 1 || need <= ws_size) break;
  }

  char* wsb = (char*)d_ws;
  unsigned short* part = (unsigned short*)wsb;
  size_t off = (size_t)nchunk * perChunk;
  float* percls_part = (float*)(wsb + off); off += (size_t)nchunk * K_CLASSES * D * sizeof(float);
  int* counts_part = (int*)(wsb + off);     off += (size_t)nchunk * K_CLASSES * sizeof(int);
  int* counts_total = (int*)(wsb + off);    off += K_CLASSES * sizeof(int);
  float* ld = (float*)(wsb + off);          off += 64 * sizeof(float);
  float* gram = (float*)(wsb + ((off + 255) & ~(size_t)255));

  const int chunkRows = (m + nchunk - 1) / nchunk;

  class_gram_kernel<<<dim3(nchunk, K_CLASSES), 256, 0, stream>>>(
      Z, Y, part, counts_part, percls_part, m, chunkRows);
  reduce1_kernel<<<dim3(16, K_CLASSES), 256, 0, stream>>>(
      part, (float4*)ztpiz, nchunk);
  reduce2_kernel<<<65, 256, 0, stream>>>(ztpiz, gram, counts_part, counts_total,
                                         percls_part, out + 1 + K_CLASSES * D * D,
                                         nchunk, m);
  chol_kernel<<<K_CLASSES + 1, 512, 0, stream>>>(ztpiz, gram, counts_total, ld, m);
  finalize_kernel<<<1, 64, 0, stream>>>(ld, counts_total, out, m);
}

// Round 18
// 73.372 us; speedup vs baseline: 1.8032x; 1.1520x over previous
//
#include <hip/hip_runtime.h>

#define K_CLASSES 32
#define D 128
#define EPSv 0.5f
#define ZPAD 42   // shorts per row: 21 dwords, coprime with 32 banks
#define WIN 4096  // window rows per list build (list LDS capacity)

typedef __attribute__((ext_vector_type(8))) short short8;
typedef __attribute__((ext_vector_type(4))) float f32x4;

// fp32 -> bf16 round-to-nearest-even
static __device__ inline unsigned short f2bf(float f) {
  union { float f; unsigned u; } x; x.f = f;
  unsigned r = x.u + 0x7FFFu + ((x.u >> 16) & 1u);
  return (unsigned short)(r >> 16);
}
static __device__ inline float bf2f(unsigned short h) {
  union { unsigned u; float f; } x;
  x.u = (unsigned)h << 16;
  return x.f;
}

// ---------------------------------------------------------------------------
// Partial per-class Gram via bf16 MFMA (unchanged from round 17).
// ---------------------------------------------------------------------------
__global__ __launch_bounds__(256) void class_gram_kernel(
    const float* __restrict__ Z, const int* __restrict__ Y,
    unsigned short* __restrict__ part, int* __restrict__ counts_part,
    float* __restrict__ percls_part, int m, int chunkRows) {
  const int k = blockIdx.y;
  const int c = blockIdx.x;
  const int tid = threadIdx.x;
  const int lane = tid & 63;
  const int w = tid >> 6;

  const int rowStart = c * chunkRows;
  const int rowEnd = min(m, rowStart + chunkRows);

  __shared__ int list[WIN];
  __shared__ unsigned short zs[128][ZPAD];
  __shared__ int wsum[4];

  const int p = tid >> 4;
  const int part16 = tid & 15;
  const int l15 = lane & 15;
  const int kb = (lane >> 4) * 8;
  const int rb0 = w * 2, rb1 = w * 2 + 1;

  f32x4 acc0[8], acc1[8];
#pragma unroll
  for (int cb = 0; cb < 8; ++cb) { acc0[cb] = (f32x4)(0.f); acc1[cb] = (f32x4)(0.f); }
  float colacc[8];
#pragma unroll
  for (int j = 0; j < 8; ++j) colacc[j] = 0.f;

  int matched = 0;

#define LOAD_STAGE(d0, d1, stidx)                                   \
  {                                                                 \
    _Pragma("unroll") for (int j = 0; j < 8; ++j) { d0[j] = 0.f; d1[j] = 0.f; } \
    if ((stidx) < nst) {                                            \
      const int i0 = ((stidx) << 5) + p * 2;                        \
      const int r0 = list[i0];                                      \
      const int r1 = list[i0 + 1];                                  \
      if (r0 >= 0) {                                                \
        const float* zp = Z + (size_t)r0 * D + part16 * 8;          \
        *(float4*)&d0[0] = *(const float4*)zp;                      \
        *(float4*)&d0[4] = *(const float4*)(zp + 4);                \
      }                                                             \
      if (r1 >= 0) {                                                \
        const float* zp = Z + (size_t)r1 * D + part16 * 8;          \
        *(float4*)&d1[0] = *(const float4*)zp;                      \
        *(float4*)&d1[4] = *(const float4*)(zp + 4);                \
      }                                                             \
    }                                                               \
  }

#define STAGE_BODY(s0, s1)                                          \
  {                                                                 \
    _Pragma("unroll") for (int j = 0; j < 8; ++j) colacc[j] += s0[j] + s1[j]; \
    __syncthreads();                                                \
    _Pragma("unroll") for (int j = 0; j < 8; ++j) {                 \
      const unsigned pk = (unsigned)f2bf(s0[j]) | ((unsigned)f2bf(s1[j]) << 16); \
      *(unsigned*)&zs[part16 * 8 + j][2 * p] = pk;                  \
    }                                                               \
    __syncthreads();                                                \
  }

#define MFMA_BODY()                                                 \
  {                                                                 \
    short8 fragC[8];                                                \
    _Pragma("unroll") for (int fb = 0; fb < 8; ++fb)                \
      fragC[fb] = *(const short8*)&zs[fb * 16 + l15][kb];           \
    const short8 fragR0 = *(const short8*)&zs[rb0 * 16 + l15][kb];  \
    const short8 fragR1 = *(const short8*)&zs[rb1 * 16 + l15][kb];  \
    _Pragma("unroll") for (int cb = 0; cb < 8; ++cb) {              \
      acc0[cb] = __builtin_amdgcn_mfma_f32_16x16x32_bf16(fragR0, fragC[cb], acc0[cb], 0, 0, 0); \
      acc1[cb] = __builtin_amdgcn_mfma_f32_16x16x32_bf16(fragR1, fragC[cb], acc1[cb], 0, 0, 0); \
    }                                                               \
  }

  for (int w0 = rowStart; w0 < rowEnd; w0 += WIN) {
    const int wend = min(w0 + WIN, rowEnd);
    __syncthreads();

    int run = 0;
    for (int base = w0; base < wend; base += 2048) {
      const int start = base + tid * 8;
      int yv[8];
      if (((start & 3) == 0) && start + 8 <= wend) {
        const int4 ya = *(const int4*)(Y + start);
        const int4 yb = *(const int4*)(Y + start + 4);
        yv[0] = ya.x; yv[1] = ya.y; yv[2] = ya.z; yv[3] = ya.w;
        yv[4] = yb.x; yv[5] = yb.y; yv[6] = yb.z; yv[7] = yb.w;
      } else {
#pragma unroll
        for (int e = 0; e < 8; ++e) {
          const int r = start + e;
          yv[e] = (r < wend) ? Y[r] : -1;
        }
      }
      int cnt = 0;
#pragma unroll
      for (int e = 0; e < 8; ++e) cnt += (yv[e] == k) ? 1 : 0;
      int cs = cnt;
#pragma unroll
      for (int off = 1; off < 64; off <<= 1) {
        const int nbr = __shfl_up(cs, off);
        if (lane >= off) cs += nbr;
      }
      if (lane == 63) wsum[w] = cs;
      const int excl = cs - cnt;
      __syncthreads();
      int woff = 0, ctot = 0;
#pragma unroll
      for (int ww = 0; ww < 4; ++ww) {
        const int v = wsum[ww];
        if (ww < w) woff += v;
        ctot += v;
      }
      __syncthreads();
      int pos = run + woff + excl;
#pragma unroll
      for (int e = 0; e < 8; ++e) {
        if (yv[e] == k) { list[pos] = start + e; ++pos; }
      }
      run += ctot;
    }
    const int total = run;
    matched += total;
    const int padded = (total + 31) & ~31;
    for (int i = total + tid; i < padded; i += 256) list[i] = -1;
    __syncthreads();

    const int nst = padded >> 5;
    float vA0[8], vA1[8], vB0[8], vB1[8];
    LOAD_STAGE(vA0, vA1, 0);
    LOAD_STAGE(vB0, vB1, 1);

    for (int st = 0; st < nst; st += 2) {
      STAGE_BODY(vA0, vA1);
      LOAD_STAGE(vA0, vA1, st + 2);
      MFMA_BODY();
      if (st + 1 < nst) {
        STAGE_BODY(vB0, vB1);
        LOAD_STAGE(vB0, vB1, st + 3);
        MFMA_BODY();
      }
    }
  }

  // ---- write partial Gram as bf16 (owner writes, no atomics) ----
  unsigned short* dst = part + ((size_t)c * K_CLASSES + k) * (D * D);
  const int l4 = lane >> 4;
#pragma unroll
  for (int cb = 0; cb < 8; ++cb)
#pragma unroll
    for (int q = 0; q < 4; ++q) {
      dst[(rb0 * 16 + l4 * 4 + q) * D + cb * 16 + l15] = f2bf(acc0[cb][q]);
      dst[(rb1 * 16 + l4 * 4 + q) * D + cb * 16 + l15] = f2bf(acc1[cb][q]);
    }

  __syncthreads();
  float* cred = (float*)&zs[0][0];
#pragma unroll
  for (int j = 0; j < 8; ++j) cred[p * 128 + part16 * 8 + j] = colacc[j];
  __syncthreads();
  if (tid < 128) {
    float s = 0.f;
#pragma unroll
    for (int pp = 0; pp < 16; ++pp) s += cred[pp * 128 + tid];
    percls_part[(c * K_CLASSES + k) * D + tid] = s;
  }
  if (tid == 0) counts_part[c * K_CLASSES + k] = matched;
}

// ---------------------------------------------------------------------------
// R1: ztpiz[k][e] = sum_c bf2f(part[c][k][e]). Grid (16, K).
// ---------------------------------------------------------------------------
__global__ __launch_bounds__(256) void reduce1_kernel(
    const unsigned short* __restrict__ part, float4* __restrict__ ztpiz,
    int nchunk) {
  const int k = blockIdx.y;
  const int e4 = blockIdx.x * 256 + threadIdx.x;
  float4 s = make_float4(0.f, 0.f, 0.f, 0.f);
  for (int c = 0; c < nchunk; ++c) {
    const ushort4 v = *(const ushort4*)(part +
        ((size_t)c * K_CLASSES + k) * (D * D) + (size_t)e4 * 4);
    s.x += bf2f(v.x); s.y += bf2f(v.y); s.z += bf2f(v.z); s.w += bf2f(v.w);
  }
  ztpiz[(size_t)k * (D * D / 4) + e4] = s;
}

// ---------------------------------------------------------------------------
// R2: blocks 0..63: gram[e] = sum_k ztpiz[k][e] (parallel, L2-hot).
//     block 64: Z_mean -> out, counts_total.
// ---------------------------------------------------------------------------
__global__ __launch_bounds__(256) void reduce2_kernel(
    const float* __restrict__ ztpiz, float* __restrict__ gram,
    const int* __restrict__ counts_part, int* __restrict__ counts_total,
    const float* __restrict__ percls_part, float* __restrict__ zmean_out,
    int nchunk, int m) {
  if (blockIdx.x < 64) {
    const int e = blockIdx.x * 256 + threadIdx.x;
    float g = 0.f;
#pragma unroll
    for (int k = 0; k < K_CLASSES; ++k) g += ztpiz[(size_t)k * D * D + e];
    gram[e] = g;
  } else {
    __shared__ float buf[256];
    const int col = threadIdx.x & 127;
    const int half = threadIdx.x >> 7;
    const int np = nchunk * K_CLASSES;
    float s0 = 0.f, s1 = 0.f, s2 = 0.f, s3 = 0.f;
    float s4 = 0.f, s5 = 0.f, s6 = 0.f, s7 = 0.f;
    int i = half;
    for (; i + 14 < np; i += 16) {
      s0 += percls_part[(i)*D + col];
      s1 += percls_part[(i + 2) * D + col];
      s2 += percls_part[(i + 4) * D + col];
      s3 += percls_part[(i + 6) * D + col];
      s4 += percls_part[(i + 8) * D + col];
      s5 += percls_part[(i + 10) * D + col];
      s6 += percls_part[(i + 12) * D + col];
      s7 += percls_part[(i + 14) * D + col];
    }
    for (; i < np; i += 2) s0 += percls_part[i * D + col];
    buf[threadIdx.x] = ((s0 + s1) + (s2 + s3)) + ((s4 + s5) + (s6 + s7));
    __syncthreads();
    if (threadIdx.x < 128)
      zmean_out[threadIdx.x] = (buf[threadIdx.x] + buf[threadIdx.x + 128]) / (float)m;
    if (threadIdx.x < K_CLASSES) {
      int t = 0;
      for (int c = 0; c < nchunk; ++c) t += counts_part[c * K_CLASSES + threadIdx.x];
      counts_total[threadIdx.x] = t;
    }
  }
}

// ---------------------------------------------------------------------------
// Blocked Cholesky of I + s*G: 2 phases per rank-8 step.
// Each PANEL thread redundantly factors the 8x8 diag from diag8 (LDS
// broadcast reads) into a private TRI(36) register array -- no shuffles,
// no cross-thread serialization -- then solves its 4 rows directly.
// The separate factor phase, l11s and invd are gone. Trailing phase stages
// the next diag (as r13). ct=15 diag handled by a post-loop tail (tid 0).
// Barriers: 1 prologue + 15*2 + 1 tail = 32 (r13: 48).
// ---------------------------------------------------------------------------
#define TRI(i, j) ((i) * ((i) + 1) / 2 + (j))
__global__ __launch_bounds__(512) void chol_kernel(const float* __restrict__ ztpiz,
                                                   const float* __restrict__ gram,
                                                   const int* __restrict__ counts,
                                                   float* __restrict__ ld, int m) {
  const int b = blockIdx.x;
  __shared__ float diag8[8][8];
  __shared__ float diagv[D];
  __shared__ float panT[8][132];
  __shared__ float red[128];

  const int tid = threadIdx.x;

  int tcb = 0, trb = 0;
  bool valid = false;
  {
    int cum = 0;
    for (int c = 0; c < 16; ++c) {
      const int cnt = 32 - 2 * c;
      if (tid >= cum && tid < cum + cnt) {
        tcb = c;
        trb = 2 * c + (tid - cum);
        valid = true;
      }
      cum += cnt;
    }
  }
  const int R = trb * 4, C = tcb * 8;

  const float* src;
  float sc;
  if (b == 0) {
    src = gram;
    sc = (float)D / ((float)m * EPSv);
  } else {
    src = ztpiz + (size_t)(b - 1) * D * D;
    const float cf = (float)counts[b - 1] + 1e-8f;
    sc = (float)D / (cf * EPSv);
  }

  float a[4][8];
  if (valid) {
#pragma unroll
    for (int i = 0; i < 4; ++i) {
      const float* sp = src + (size_t)(R + i) * D + C;
      float tv[8];
      *(float4*)&tv[0] = *(const float4*)sp;
      *(float4*)&tv[4] = *(const float4*)(sp + 4);
#pragma unroll
      for (int j = 0; j < 8; ++j)
        a[i][j] = sc * tv[j] + ((R + i) == (C + j) ? 1.0f : 0.0f);
    }
  }

  // prologue: stage diag block 0
  if (valid && tcb == 0 && trb <= 1) {
    const int hb = trb * 4;
#pragma unroll
    for (int i = 0; i < 4; ++i) {
      *(float4*)&diag8[hb + i][0] = *(float4*)&a[i][0];
      *(float4*)&diag8[hb + i][4] = *(float4*)&a[i][4];
    }
  }
  __syncthreads();

// factor diag8 (LDS) into private f[36]/dr[8]; all indices static
#define LOCAL_FACTOR(f, dr)                                         \
  {                                                                 \
    _Pragma("unroll")                                               \
    for (int i = 0; i < 8; ++i)                                     \
      _Pragma("unroll")                                             \
      for (int j = 0; j < 8; ++j)                                   \
        if (j <= i) f[TRI(i, j)] = diag8[i][j];                     \
    _Pragma("unroll")                                               \
    for (int kk = 0; kk < 8; ++kk) {                                \
      const float x = f[TRI(kk, kk)];                               \
      const float r = rsqrtf(x);                                    \
      f[TRI(kk, kk)] = x * r;                                       \
      dr[kk] = r;                                                   \
      _Pragma("unroll")                                             \
      for (int i = 0; i < 8; ++i)                                   \
        if (i > kk) f[TRI(i, kk)] *= r;                             \
      _Pragma("unroll")                                             \
      for (int j = 0; j < 8; ++j)                                   \
        if (j > kk)                                                 \
          _Pragma("unroll")                                         \
          for (int i = 0; i < 8; ++i)                               \
            if (i >= j) f[TRI(i, j)] = fmaf(-f[TRI(i, kk)], f[TRI(j, kk)], f[TRI(i, j)]); \
    }                                                               \
  }

  for (int ct = 0; ct < 15; ++ct) {
    // --- phase A: panel solve with redundant private diag factor ---
    if (valid && tcb == ct && trb >= 2 * ct + 2) {
      float f[36], dr[8];
      LOCAL_FACTOR(f, dr);
      if (trb == 2 * ct + 2) {
#pragma unroll
        for (int kk = 0; kk < 8; ++kk) diagv[8 * ct + kk] = f[TRI(kk, kk)];
      }
#pragma unroll
      for (int j = 0; j < 8; ++j) {
#pragma unroll
        for (int i = 0; i < 4; ++i) {
          float x = a[i][j];
#pragma unroll
          for (int q = 0; q < 8; ++q)
            if (q < j) x = fmaf(-a[i][q], f[TRI(j, q)], x);
          a[i][j] = x * dr[j];
        }
      }
#pragma unroll
      for (int pq = 0; pq < 8; ++pq) {
        float t4[4];
#pragma unroll
        for (int i = 0; i < 4; ++i) t4[i] = a[i][pq];
        *(float4*)&panT[pq][R] = *(float4*)&t4[0];
      }
    }
    __syncthreads();

    // --- phase B: rank-8 trailing + stage next diag ---
    if (valid && tcb >= ct + 1) {
#pragma unroll 4
      for (int pq = 0; pq < 8; ++pq) {
        float cr4[4], cc8[8];
        *(float4*)&cr4[0] = *(const float4*)&panT[pq][R];
        *(float4*)&cc8[0] = *(const float4*)&panT[pq][C];
        *(float4*)&cc8[4] = *(const float4*)&panT[pq][C + 4];
#pragma unroll
        for (int i = 0; i < 4; ++i)
#pragma unroll
          for (int j = 0; j < 8; ++j)
            a[i][j] = fmaf(-cr4[i], cc8[j], a[i][j]);
      }
      if (tcb == ct + 1 && trb <= 2 * ct + 3) {
        const int hb = (trb - 2 * (ct + 1)) * 4;
#pragma unroll
        for (int i = 0; i < 4; ++i) {
          *(float4*)&diag8[hb + i][0] = *(float4*)&a[i][0];
          *(float4*)&diag8[hb + i][4] = *(float4*)&a[i][4];
        }
      }
    }
    __syncthreads();
  }

  // --- tail: factor the last (ct=15) diag block for diagv[120..127] ---
  if (tid == 0) {
    float f[36], dr[8];
    LOCAL_FACTOR(f, dr);
#pragma unroll
    for (int kk = 0; kk < 8; ++kk) diagv[120 + kk] = f[TRI(kk, kk)];
  }
  __syncthreads();

  if (tid < 128) red[tid] = logf(diagv[tid]);
  __syncthreads();
  for (int off = 64; off > 0; off >>= 1) {
    if (tid < off) red[tid] += red[tid + off];
    __syncthreads();
  }
  if (tid == 0) ld[b] = 2.0f * red[0];
}

// ---------------------------------------------------------------------------
// Loss scalar only. One wave.
// ---------------------------------------------------------------------------
__global__ void finalize_kernel(const float* __restrict__ ldv,
                                const int* __restrict__ counts,
                                float* __restrict__ out, int m) {
  const int lane = threadIdx.x & 63;
  float v = 0.f;
  if (lane < K_CLASSES)
    v = ldv[lane + 1] * (((float)counts[lane] + 1e-8f) / (float)m);
#pragma unroll
  for (int off = 32; off > 0; off >>= 1) v += __shfl_down(v, off);
  if (lane == 0) out[0] = -0.5f * ldv[0] + 0.5f * v;
}

extern "C" void kernel_launch(void* const* d_in, const int* in_sizes, int n_in,
                              void* d_out, int out_size, void* d_ws, size_t ws_size,
                              hipStream_t stream) {
  const float* Z = (const float*)d_in[0];
  const int* Y = (const int*)d_in[1];
  float* out = (float*)d_out;
  const int m = in_sizes[0] / D;

  float* ztpiz = out + 1;  // (K, D, D)

  const size_t perChunk = (size_t)K_CLASSES * D * D * sizeof(unsigned short);
  int nchunk = 16;
  for (;; nchunk >>= 1) {
    const size_t need = (size_t)nchunk * perChunk +
                        (size_t)nchunk * K_CLASSES * (D + 1) * sizeof(float) +
                        K_CLASSES * sizeof(int) + 64 * 1024 + 4096;
    if (nchunk == 1 || need <= ws_size) break;
  }

  char* wsb = (char*)d_ws;
  unsigned short* part = (unsigned short*)wsb;
  size_t off = (size_t)nchunk * perChunk;
  float* percls_part = (float*)(wsb + off); off += (size_t)nchunk * K_CLASSES * D * sizeof(float);
  int* counts_part = (int*)(wsb + off);     off += (size_t)nchunk * K_CLASSES * sizeof(int);
  int* counts_total = (int*)(wsb + off);    off += K_CLASSES * sizeof(int);
  float* ld = (float*)(wsb + off);          off += 64 * sizeof(float);
  float* gram = (float*)(wsb + ((off + 255) & ~(size_t)255));

  const int chunkRows = (m + nchunk - 1) / nchunk;

  class_gram_kernel<<<dim3(nchunk, K_CLASSES), 256, 0, stream>>>(
      Z, Y, part, counts_part, percls_part, m, chunkRows);
  reduce1_kernel<<<dim3(16, K_CLASSES), 256, 0, stream>>>(
      part, (float4*)ztpiz, nchunk);
  reduce2_kernel<<<65, 256, 0, stream>>>(ztpiz, gram, counts_part, counts_total,
                                         percls_part, out + 1 + K_CLASSES * D * D,
                                         nchunk, m);
  chol_kernel<<<K_CLASSES + 1, 512, 0, stream>>>(ztpiz, gram, counts_total, ld, m);
  finalize_kernel<<<1, 64, 0, stream>>>(ld, counts_total, out, m);
}